// Round 1
// baseline (2488.032 us; speedup 1.0000x reference)
//
#include <hip/hip_runtime.h>

// 2-layer hetero GraphSAGE, fp32.
// Decomposition: mean_agg(x)@Wl == mean_agg(x@Wl)  -> transform nodes first,
// aggregate 64-wide transformed rows over edges (atomic scatter-add), then
// fuse (agg/deg + b + x_dst@Wr [+relu]) in one combine kernel per node type.

// ---------------- degree count ----------------
__global__ __launch_bounds__(256) void k_deg(const int* __restrict__ src,
                                             const int* __restrict__ dst,
                                             int* __restrict__ deg_u,
                                             int* __restrict__ deg_p, int E) {
    int e = blockIdx.x * blockDim.x + threadIdx.x;
    if (e < E) {
        atomicAdd(&deg_u[src[e]], 1);
        atomicAdd(&deg_p[dst[e]], 1);
    }
}

// ---------------- y[n][c] = sum_k x[n][k] * W[k][c], H=64 cols ----------------
template <int K>
__global__ __launch_bounds__(256) void k_transform(const float* __restrict__ x,
                                                   const float* __restrict__ W,
                                                   float* __restrict__ y, int N) {
    __shared__ float Ws[K * 64];
    __shared__ float xs[4][K];
    const int tid = threadIdx.x;
    for (int i = tid; i < K * 64; i += 256) Ws[i] = W[i];
    const int r = tid >> 6, c = tid & 63;
    const int row0 = blockIdx.x * 4;
    for (int i = tid; i < 4 * K; i += 256) {
        int rr = i / K, kk = i % K;
        int row = row0 + rr;
        xs[rr][kk] = (row < N) ? x[(long long)row * K + kk] : 0.f;
    }
    __syncthreads();
    const int row = row0 + r;
    if (row >= N) return;
    float acc = 0.f;
#pragma unroll 8
    for (int k = 0; k < K; ++k) acc += xs[r][k] * Ws[k * 64 + c];
    y[(long long)row * 64 + c] = acc;
}

// ---------------- agg[sidx[e]][c] += y[gidx[e]][c] ----------------
__global__ __launch_bounds__(256) void k_scatter(const float* __restrict__ y,
                                                 const int* __restrict__ gidx,
                                                 const int* __restrict__ sidx,
                                                 float* __restrict__ agg,
                                                 long long n64) {
    long long t = (long long)blockIdx.x * 256 + threadIdx.x;
    if (t >= n64) return;
    int e = (int)(t >> 6);
    int c = (int)(t & 63);
    int g = gidx[e];
    int s = sidx[e];
    atomicAdd(&agg[(long long)s * 64 + c], y[(long long)g * 64 + c]);
}

// ------- h[n][c] = act( agg[n][c]/max(deg,1) + b[c] + sum_k xdst[n][k]*Wr[k][c] ) -------
template <int K, bool RELU>
__global__ __launch_bounds__(256) void k_combine(const float* __restrict__ xdst,
                                                 const float* __restrict__ Wr,
                                                 const float* __restrict__ bias,
                                                 const float* __restrict__ agg,
                                                 const int* __restrict__ deg,
                                                 float* __restrict__ h, int N) {
    __shared__ float Ws[K * 64];
    __shared__ float xs[4][K];
    const int tid = threadIdx.x;
    for (int i = tid; i < K * 64; i += 256) Ws[i] = Wr[i];
    const int r = tid >> 6, c = tid & 63;
    const int row0 = blockIdx.x * 4;
    for (int i = tid; i < 4 * K; i += 256) {
        int rr = i / K, kk = i % K;
        int row = row0 + rr;
        xs[rr][kk] = (row < N) ? xdst[(long long)row * K + kk] : 0.f;
    }
    __syncthreads();
    const int row = row0 + r;
    if (row >= N) return;
    float acc = 0.f;
#pragma unroll 8
    for (int k = 0; k < K; ++k) acc += xs[r][k] * Ws[k * 64 + c];
    float dinv = 1.0f / (float)max(deg[row], 1);
    float v = acc + bias[c] + agg[(long long)row * 64 + c] * dinv;
    if (RELU) v = fmaxf(v, 0.f);
    h[(long long)row * 64 + c] = v;
}

// ---------------- out[e] = dot64(hu[lu[e]], hp[lp[e]]) ----------------
__global__ __launch_bounds__(256) void k_classify(const float* __restrict__ hu,
                                                  const float* __restrict__ hp,
                                                  const int* __restrict__ lu,
                                                  const int* __restrict__ lp,
                                                  float* __restrict__ out, int EL) {
    long long t = (long long)blockIdx.x * 256 + threadIdx.x;
    int e = (int)(t >> 6);
    int c = (int)(t & 63);
    if (e >= EL) return;
    int u = lu[e], p = lp[e];
    float v = hu[(long long)u * 64 + c] * hp[(long long)p * 64 + c];
#pragma unroll
    for (int m = 32; m > 0; m >>= 1) v += __shfl_xor(v, m, 64);
    if (c == 0) out[e] = v;
}

extern "C" void kernel_launch(void* const* d_in, const int* in_sizes, int n_in,
                              void* d_out, int out_size, void* d_ws, size_t ws_size,
                              hipStream_t stream) {
    const float* x_user    = (const float*)d_in[0];
    const float* x_product = (const float*)d_in[1];
    const float* W1bl = (const float*)d_in[2];
    const float* b1b  = (const float*)d_in[3];
    const float* W1br = (const float*)d_in[4];
    const float* W1rl = (const float*)d_in[5];
    const float* b1r  = (const float*)d_in[6];
    const float* W1rr = (const float*)d_in[7];
    const float* W2bl = (const float*)d_in[8];
    const float* b2b  = (const float*)d_in[9];
    const float* W2br = (const float*)d_in[10];
    const float* W2rl = (const float*)d_in[11];
    const float* b2r  = (const float*)d_in[12];
    const float* W2rr = (const float*)d_in[13];
    const int* esrc = (const int*)d_in[14];
    const int* edst = (const int*)d_in[15];
    const int* lu   = (const int*)d_in[16];
    const int* lp   = (const int*)d_in[17];

    const int NU = in_sizes[0] / 64;
    const int NP = in_sizes[1] / 128;
    const int E  = in_sizes[14];
    const int EL = in_sizes[16];

    // ---- workspace layout (~129 MB) ----
    char* ws = (char*)d_ws;
    size_t off = 0;
    auto alloc = [&](size_t bytes) -> void* {
        void* p = ws + off;
        off += (bytes + 255) & ~(size_t)255;
        return p;
    };
    int*   deg_u = (int*)alloc((size_t)NU * 4);
    int*   deg_p = (int*)alloc((size_t)NP * 4);
    float* y_a   = (float*)alloc((size_t)NU * 64 * 4);  // user-side transforms; later h_p2
    float* y_b   = (float*)alloc((size_t)NU * 64 * 4);  // product-side transforms; later h_u2
    float* agg_u = (float*)alloc((size_t)NU * 64 * 4);
    float* agg_p = (float*)alloc((size_t)NP * 64 * 4);
    float* h_u   = (float*)alloc((size_t)NU * 64 * 4);
    float* h_p   = (float*)alloc((size_t)NP * 64 * 4);
    float* h_p2 = y_a;  // safe: y_u2 dead after its scatter; h_p2 written after
    float* h_u2 = y_b;  // safe: y_p2 dead after its scatter; h_u2 written after

    const long long n64e = (long long)E * 64;
    const int sblocks = (int)((n64e + 255) / 256);
    const long long n64l = (long long)EL * 64;
    const int cblocks = (int)((n64l + 255) / 256);

    // degrees (shared by both layers)
    hipMemsetAsync(deg_u, 0, (size_t)NU * 4, stream);
    hipMemsetAsync(deg_p, 0, (size_t)NP * 4, stream);
    k_deg<<<(E + 255) / 256, 256, 0, stream>>>(esrc, edst, deg_u, deg_p, E);

    // ---- layer 1, buys (user -> product) ----
    k_transform<64><<<(NU + 3) / 4, 256, 0, stream>>>(x_user, W1bl, y_a, NU);
    hipMemsetAsync(agg_p, 0, (size_t)NP * 64 * 4, stream);
    k_scatter<<<sblocks, 256, 0, stream>>>(y_a, esrc, edst, agg_p, n64e);
    k_combine<128, true><<<(NP + 3) / 4, 256, 0, stream>>>(x_product, W1br, b1b, agg_p, deg_p, h_p, NP);

    // ---- layer 1, rev (product -> user) ----
    k_transform<128><<<(NP + 3) / 4, 256, 0, stream>>>(x_product, W1rl, y_b, NP);
    hipMemsetAsync(agg_u, 0, (size_t)NU * 64 * 4, stream);
    k_scatter<<<sblocks, 256, 0, stream>>>(y_b, edst, esrc, agg_u, n64e);
    k_combine<64, true><<<(NU + 3) / 4, 256, 0, stream>>>(x_user, W1rr, b1r, agg_u, deg_u, h_u, NU);

    // ---- layer 2, buys ----
    k_transform<64><<<(NU + 3) / 4, 256, 0, stream>>>(h_u, W2bl, y_a, NU);
    hipMemsetAsync(agg_p, 0, (size_t)NP * 64 * 4, stream);
    k_scatter<<<sblocks, 256, 0, stream>>>(y_a, esrc, edst, agg_p, n64e);
    k_combine<64, false><<<(NP + 3) / 4, 256, 0, stream>>>(h_p, W2br, b2b, agg_p, deg_p, h_p2, NP);

    // ---- layer 2, rev ----
    k_transform<64><<<(NP + 3) / 4, 256, 0, stream>>>(h_p, W2rl, y_b, NP);
    hipMemsetAsync(agg_u, 0, (size_t)NU * 64 * 4, stream);
    k_scatter<<<sblocks, 256, 0, stream>>>(y_b, edst, esrc, agg_u, n64e);
    k_combine<64, false><<<(NU + 3) / 4, 256, 0, stream>>>(h_u, W2rr, b2r, agg_u, deg_u, h_u2, NU);

    // ---- classifier ----
    k_classify<<<cblocks, 256, 0, stream>>>(h_u2, h_p2, lu, lp, (float*)d_out, EL);
}

// Round 2
// 1444.378 us; speedup vs baseline: 1.7226x; 1.7226x over previous
//
#include <hip/hip_runtime.h>

// 2-layer hetero GraphSAGE, fp32, CSR gather-reduce (no float atomics).
// mean_agg(x) @ Wl == mean_agg(x @ Wl): aggregate 64-wide rows; for 64-wide
// sources aggregate raw rows and fold @Wl into the combine; only the 128-wide
// x_product path transforms first.

// ---------------- degree count ----------------
__global__ __launch_bounds__(256) void k_deg(const int* __restrict__ src,
                                             const int* __restrict__ dst,
                                             int* __restrict__ deg_u,
                                             int* __restrict__ deg_p, int E) {
    int e = blockIdx.x * blockDim.x + threadIdx.x;
    if (e < E) {
        atomicAdd(&deg_u[src[e]], 1);
        atomicAdd(&deg_p[dst[e]], 1);
    }
}

// ------- ptr[n] = (disjoint region start for node n); block-scan + 1 atomic/block -------
__global__ __launch_bounds__(256) void k_offsets(const int* __restrict__ deg,
                                                 int* __restrict__ ptr,
                                                 int* __restrict__ cnt, int N) {
    __shared__ int s[256];
    __shared__ int sbase;
    int n = blockIdx.x * 256 + threadIdx.x;
    int d = (n < N) ? deg[n] : 0;
    s[threadIdx.x] = d;
    __syncthreads();
    for (int off = 1; off < 256; off <<= 1) {  // inclusive Hillis-Steele
        int v = (threadIdx.x >= off) ? s[threadIdx.x - off] : 0;
        __syncthreads();
        s[threadIdx.x] += v;
        __syncthreads();
    }
    if (threadIdx.x == 255) sbase = atomicAdd(cnt, s[255]);
    __syncthreads();
    if (n < N) ptr[n] = sbase + s[threadIdx.x] - d;  // exclusive start
}

// ------- fill both CSRs; ptr becomes END pointer after this -------
__global__ __launch_bounds__(256) void k_fill(const int* __restrict__ src,
                                              const int* __restrict__ dst,
                                              int* __restrict__ ptr_u,
                                              int* __restrict__ ptr_p,
                                              int* __restrict__ nbr_u,
                                              int* __restrict__ nbr_p, int E) {
    int e = blockIdx.x * blockDim.x + threadIdx.x;
    if (e < E) {
        int s = src[e], d = dst[e];
        nbr_p[atomicAdd(&ptr_p[d], 1)] = s;  // product -> list of user ids
        nbr_u[atomicAdd(&ptr_u[s], 1)] = d;  // user -> list of product ids
    }
}

// ------- agg[n][c] = mean over nbr list of y[nbr][c]; wave per node -------
__global__ __launch_bounds__(256) void k_gather(const float* __restrict__ y,
                                                const int* __restrict__ nbr,
                                                const int* __restrict__ endp,
                                                const int* __restrict__ deg,
                                                float* __restrict__ agg, int N) {
    int node = (blockIdx.x * 256 + threadIdx.x) >> 6;
    int lane = threadIdx.x & 63;
    if (node >= N) return;
    int d = deg[node];
    int end = endp[node];
    int j = end - d;
    float a0 = 0.f, a1 = 0.f, a2 = 0.f, a3 = 0.f;
    for (; j + 4 <= end; j += 4) {
        int g0 = nbr[j], g1 = nbr[j + 1], g2 = nbr[j + 2], g3 = nbr[j + 3];
        a0 += y[g0 * 64 + lane];
        a1 += y[g1 * 64 + lane];
        a2 += y[g2 * 64 + lane];
        a3 += y[g3 * 64 + lane];
    }
    for (; j < end; ++j) a0 += y[nbr[j] * 64 + lane];
    float s = (a0 + a1) + (a2 + a3);
    agg[node * 64 + lane] = s * (1.0f / (float)max(d, 1));
}

// ---------------- y[n][c] = sum_k x[n][k] * W[k][c] (128 -> 64) ----------------
template <int K>
__global__ __launch_bounds__(256) void k_transform(const float* __restrict__ x,
                                                   const float* __restrict__ W,
                                                   float* __restrict__ y, int N) {
    __shared__ float Ws[K * 64];
    __shared__ float xs[4][K];
    const int tid = threadIdx.x;
    for (int i = tid; i < K * 64; i += 256) Ws[i] = W[i];
    const int r = tid >> 6, c = tid & 63;
    const int row0 = blockIdx.x * 4;
    for (int i = tid; i < 4 * K; i += 256) {
        int rr = i / K, kk = i % K;
        int row = row0 + rr;
        xs[rr][kk] = (row < N) ? x[row * K + kk] : 0.f;
    }
    __syncthreads();
    const int row = row0 + r;
    if (row >= N) return;
    float acc = 0.f;
#pragma unroll 8
    for (int k = 0; k < K; ++k) acc += xs[r][k] * Ws[k * 64 + c];
    y[row * 64 + c] = acc;
}

// ------- h = act( agg@Wl + b + xdst@Wr ); safe when h aliases xdst -------
template <int K2, bool RELU>
__global__ __launch_bounds__(256) void k_combine2(const float* __restrict__ agg,
                                                  const float* __restrict__ Wl,
                                                  const float* __restrict__ bias,
                                                  const float* __restrict__ xdst,
                                                  const float* __restrict__ Wr,
                                                  float* __restrict__ h, int N) {
    __shared__ float Wls[64 * 64];
    __shared__ float Wrs[K2 * 64];
    __shared__ float as_[4][64];
    __shared__ float xs[4][K2];
    const int tid = threadIdx.x;
    for (int i = tid; i < 64 * 64; i += 256) Wls[i] = Wl[i];
    for (int i = tid; i < K2 * 64; i += 256) Wrs[i] = Wr[i];
    const int r = tid >> 6, c = tid & 63;
    const int row0 = blockIdx.x * 4;
    {
        int row = row0 + r;
        as_[r][c] = (row < N) ? agg[row * 64 + c] : 0.f;
    }
    for (int i = tid; i < 4 * K2; i += 256) {
        int rr = i / K2, kk = i % K2;
        int row = row0 + rr;
        xs[rr][kk] = (row < N) ? xdst[row * K2 + kk] : 0.f;
    }
    __syncthreads();
    const int row = row0 + r;
    if (row >= N) return;
    float acc = bias[c];
#pragma unroll 8
    for (int k = 0; k < 64; ++k) acc += as_[r][k] * Wls[k * 64 + c];
#pragma unroll 8
    for (int k = 0; k < K2; ++k) acc += xs[r][k] * Wrs[k * 64 + c];
    if (RELU) acc = fmaxf(acc, 0.f);
    h[row * 64 + c] = acc;
}

// ------- h = act( agg + b + xdst@Wr ), agg pre-transformed (L1-rev path) -------
template <bool RELU>
__global__ __launch_bounds__(256) void k_combine_id(const float* __restrict__ agg,
                                                    const float* __restrict__ bias,
                                                    const float* __restrict__ xdst,
                                                    const float* __restrict__ Wr,
                                                    float* __restrict__ h, int N) {
    __shared__ float Wrs[64 * 64];
    __shared__ float xs[4][64];
    const int tid = threadIdx.x;
    for (int i = tid; i < 64 * 64; i += 256) Wrs[i] = Wr[i];
    const int r = tid >> 6, c = tid & 63;
    const int row0 = blockIdx.x * 4;
    {
        int row = row0 + r;
        xs[r][c] = (row < N) ? xdst[row * 64 + c] : 0.f;
    }
    __syncthreads();
    const int row = row0 + r;
    if (row >= N) return;
    float acc = bias[c] + agg[row * 64 + c];
#pragma unroll 8
    for (int k = 0; k < 64; ++k) acc += xs[r][k] * Wrs[k * 64 + c];
    if (RELU) acc = fmaxf(acc, 0.f);
    h[row * 64 + c] = acc;
}

// ---------------- out[e] = dot64(hu[lu[e]], hp[lp[e]]) ----------------
__global__ __launch_bounds__(256) void k_classify(const float* __restrict__ hu,
                                                  const float* __restrict__ hp,
                                                  const int* __restrict__ lu,
                                                  const int* __restrict__ lp,
                                                  float* __restrict__ out, int EL) {
    long long t = (long long)blockIdx.x * 256 + threadIdx.x;
    int e = (int)(t >> 6);
    int c = (int)(t & 63);
    if (e >= EL) return;
    int u = lu[e], p = lp[e];
    float v = hu[u * 64 + c] * hp[p * 64 + c];
#pragma unroll
    for (int m = 32; m > 0; m >>= 1) v += __shfl_xor(v, m, 64);
    if (c == 0) out[e] = v;
}

extern "C" void kernel_launch(void* const* d_in, const int* in_sizes, int n_in,
                              void* d_out, int out_size, void* d_ws, size_t ws_size,
                              hipStream_t stream) {
    const float* x_user    = (const float*)d_in[0];
    const float* x_product = (const float*)d_in[1];
    const float* W1bl = (const float*)d_in[2];
    const float* b1b  = (const float*)d_in[3];
    const float* W1br = (const float*)d_in[4];
    const float* W1rl = (const float*)d_in[5];
    const float* b1r  = (const float*)d_in[6];
    const float* W1rr = (const float*)d_in[7];
    const float* W2bl = (const float*)d_in[8];
    const float* b2b  = (const float*)d_in[9];
    const float* W2br = (const float*)d_in[10];
    const float* W2rl = (const float*)d_in[11];
    const float* b2r  = (const float*)d_in[12];
    const float* W2rr = (const float*)d_in[13];
    const int* esrc = (const int*)d_in[14];
    const int* edst = (const int*)d_in[15];
    const int* lu   = (const int*)d_in[16];
    const int* lp   = (const int*)d_in[17];

    const int NU = in_sizes[0] / 64;
    const int NP = in_sizes[1] / 128;
    const int E  = in_sizes[14];
    const int EL = in_sizes[16];

    // ---- workspace layout (~107 MB) ----
    char* ws = (char*)d_ws;
    size_t off = 0;
    auto alloc = [&](size_t bytes) -> void* {
        void* p = ws + off;
        off += (bytes + 255) & ~(size_t)255;
        return p;
    };
    int*   deg_u = (int*)alloc((size_t)NU * 4);
    int*   deg_p = (int*)alloc((size_t)NP * 4);
    int*   ptr_u = (int*)alloc((size_t)NU * 4);
    int*   ptr_p = (int*)alloc((size_t)NP * 4);
    int*   cnt   = (int*)alloc(256);
    int*   nbr_u = (int*)alloc((size_t)E * 4);
    int*   nbr_p = (int*)alloc((size_t)E * 4);
    float* aggP  = (float*)alloc((size_t)NP * 64 * 4);
    float* aggU  = (float*)alloc((size_t)NU * 64 * 4);
    float* y_p1  = (float*)alloc((size_t)NP * 64 * 4);
    float* h_p   = (float*)alloc((size_t)NP * 64 * 4);
    float* h_u   = (float*)alloc((size_t)NU * 64 * 4);

    const int eb = (E + 255) / 256;

    // ---- CSR build (both directions), shared by both layers ----
    hipMemsetAsync(deg_u, 0, (size_t)NU * 4, stream);
    hipMemsetAsync(deg_p, 0, (size_t)NP * 4, stream);
    hipMemsetAsync(cnt, 0, 256, stream);
    k_deg<<<eb, 256, 0, stream>>>(esrc, edst, deg_u, deg_p, E);
    k_offsets<<<(NU + 255) / 256, 256, 0, stream>>>(deg_u, ptr_u, &cnt[0], NU);
    k_offsets<<<(NP + 255) / 256, 256, 0, stream>>>(deg_p, ptr_p, &cnt[1], NP);
    k_fill<<<eb, 256, 0, stream>>>(esrc, edst, ptr_u, ptr_p, nbr_u, nbr_p, E);
    // ptr_* now hold END offsets; gather uses end - deg.

    // ---- layer 1, buys (user -> product): aggregate raw x_user, fold W1bl in ----
    k_gather<<<(NP + 3) / 4, 256, 0, stream>>>(x_user, nbr_p, ptr_p, deg_p, aggP, NP);
    k_combine2<128, true><<<(NP + 3) / 4, 256, 0, stream>>>(aggP, W1bl, b1b, x_product, W1br, h_p, NP);

    // ---- layer 1, rev (product -> user): transform 128->64 first, then aggregate ----
    k_transform<128><<<(NP + 3) / 4, 256, 0, stream>>>(x_product, W1rl, y_p1, NP);
    k_gather<<<(NU + 3) / 4, 256, 0, stream>>>(y_p1, nbr_u, ptr_u, deg_u, aggU, NU);
    k_combine_id<true><<<(NU + 3) / 4, 256, 0, stream>>>(aggU, b1r, x_user, W1rr, h_u, NU);

    // ---- layer 2: both gathers first, then in-place combines ----
    k_gather<<<(NP + 3) / 4, 256, 0, stream>>>(h_u, nbr_p, ptr_p, deg_p, aggP, NP);
    k_gather<<<(NU + 3) / 4, 256, 0, stream>>>(h_p, nbr_u, ptr_u, deg_u, aggU, NU);
    k_combine2<64, false><<<(NP + 3) / 4, 256, 0, stream>>>(aggP, W2bl, b2b, h_p, W2br, h_p, NP);
    k_combine2<64, false><<<(NU + 3) / 4, 256, 0, stream>>>(aggU, W2rl, b2r, h_u, W2rr, h_u, NU);

    // ---- classifier ----
    const long long n64l = (long long)EL * 64;
    k_classify<<<(int)((n64l + 255) / 256), 256, 0, stream>>>(h_u, h_p, lu, lp, (float*)d_out, EL);
}

// Round 3
// 1210.514 us; speedup vs baseline: 2.0554x; 1.1932x over previous
//
#include <hip/hip_runtime.h>

// 2-layer hetero GraphSAGE, fp32 compute, bf16 gather sources, CSR gather-reduce.
// mean_agg(x) @ Wl == mean_agg(x @ Wl). Aggregation row tables are stored as
// bf16 shadows (halves random-row gather traffic); all matmuls/combines fp32.

using u16 = unsigned short;
using u32 = unsigned int;

__device__ __forceinline__ u16 bf16r(float f) {            // round-to-nearest-even
    u32 b = __float_as_uint(f);
    b += 0x7fffu + ((b >> 16) & 1u);
    return (u16)(b >> 16);
}
__device__ __forceinline__ float bflo(u32 u) { return __uint_as_float(u << 16); }
__device__ __forceinline__ float bfhi(u32 u) { return __uint_as_float(u & 0xffff0000u); }

// ---------------- degree count, 4 edges/thread ----------------
__global__ __launch_bounds__(256) void k_deg4(const int4* __restrict__ src4,
                                              const int4* __restrict__ dst4,
                                              int* __restrict__ deg_u,
                                              int* __restrict__ deg_p, int E4) {
    int i = blockIdx.x * 256 + threadIdx.x;
    if (i >= E4) return;
    int4 s = src4[i], d = dst4[i];
    atomicAdd(&deg_u[s.x], 1); atomicAdd(&deg_u[s.y], 1);
    atomicAdd(&deg_u[s.z], 1); atomicAdd(&deg_u[s.w], 1);
    atomicAdd(&deg_p[d.x], 1); atomicAdd(&deg_p[d.y], 1);
    atomicAdd(&deg_p[d.z], 1); atomicAdd(&deg_p[d.w], 1);
}
__global__ __launch_bounds__(64) void k_deg_tail(const int* __restrict__ src,
                                                 const int* __restrict__ dst,
                                                 int* __restrict__ deg_u,
                                                 int* __restrict__ deg_p,
                                                 int e0, int E) {
    int e = e0 + threadIdx.x;
    if (e < E) { atomicAdd(&deg_u[src[e]], 1); atomicAdd(&deg_p[dst[e]], 1); }
}

// ------- exclusive start offsets; block-scan + 1 atomic/block -------
__global__ __launch_bounds__(256) void k_offsets(const int* __restrict__ deg,
                                                 int* __restrict__ ptr,
                                                 int* __restrict__ cnt, int N) {
    __shared__ int s[256];
    __shared__ int sbase;
    int n = blockIdx.x * 256 + threadIdx.x;
    int d = (n < N) ? deg[n] : 0;
    s[threadIdx.x] = d;
    __syncthreads();
    for (int off = 1; off < 256; off <<= 1) {
        int v = (threadIdx.x >= off) ? s[threadIdx.x - off] : 0;
        __syncthreads();
        s[threadIdx.x] += v;
        __syncthreads();
    }
    if (threadIdx.x == 255) sbase = atomicAdd(cnt, s[255]);
    __syncthreads();
    if (n < N) ptr[n] = sbase + s[threadIdx.x] - d;
}

// ------- fill both CSRs, 4 edges/thread; ptr becomes END after -------
__global__ __launch_bounds__(256) void k_fill4(const int4* __restrict__ src4,
                                               const int4* __restrict__ dst4,
                                               int* __restrict__ ptr_u,
                                               int* __restrict__ ptr_p,
                                               int* __restrict__ nbr_u,
                                               int* __restrict__ nbr_p, int E4) {
    int i = blockIdx.x * 256 + threadIdx.x;
    if (i >= E4) return;
    int4 s = src4[i], d = dst4[i];
    int p0 = atomicAdd(&ptr_p[d.x], 1), p1 = atomicAdd(&ptr_p[d.y], 1);
    int p2 = atomicAdd(&ptr_p[d.z], 1), p3 = atomicAdd(&ptr_p[d.w], 1);
    int q0 = atomicAdd(&ptr_u[s.x], 1), q1 = atomicAdd(&ptr_u[s.y], 1);
    int q2 = atomicAdd(&ptr_u[s.z], 1), q3 = atomicAdd(&ptr_u[s.w], 1);
    nbr_p[p0] = s.x; nbr_p[p1] = s.y; nbr_p[p2] = s.z; nbr_p[p3] = s.w;
    nbr_u[q0] = d.x; nbr_u[q1] = d.y; nbr_u[q2] = d.z; nbr_u[q3] = d.w;
}
__global__ __launch_bounds__(64) void k_fill_tail(const int* __restrict__ src,
                                                  const int* __restrict__ dst,
                                                  int* __restrict__ ptr_u,
                                                  int* __restrict__ ptr_p,
                                                  int* __restrict__ nbr_u,
                                                  int* __restrict__ nbr_p,
                                                  int e0, int E) {
    int e = e0 + threadIdx.x;
    if (e < E) {
        int s = src[e], d = dst[e];
        nbr_p[atomicAdd(&ptr_p[d], 1)] = s;
        nbr_u[atomicAdd(&ptr_u[s], 1)] = d;
    }
}

// ---------------- fp32 table -> bf16 shadow, 8 elems/thread ----------------
__global__ __launch_bounds__(256) void k_cast8(const float* __restrict__ x,
                                               u16* __restrict__ y, int n8) {
    int i = blockIdx.x * 256 + threadIdx.x;
    if (i >= n8) return;
    const float4* x4 = (const float4*)x;
    float4 a = x4[i * 2], b = x4[i * 2 + 1];
    uint4 o;
    o.x = (u32)bf16r(a.x) | ((u32)bf16r(a.y) << 16);
    o.y = (u32)bf16r(a.z) | ((u32)bf16r(a.w) << 16);
    o.z = (u32)bf16r(b.x) | ((u32)bf16r(b.y) << 16);
    o.w = (u32)bf16r(b.z) | ((u32)bf16r(b.w) << 16);
    ((uint4*)y)[i] = o;
}

// ---------------- y_bf[n][c] = bf16( sum_k x[n][k] * W[k][c] ), K=128 ----------------
__global__ __launch_bounds__(256) void k_transform_bf128(const float* __restrict__ x,
                                                         const float* __restrict__ W,
                                                         u16* __restrict__ ybf, int N) {
    __shared__ float Ws[128 * 64];
    __shared__ float xs[4][128];
    const int tid = threadIdx.x;
    for (int i = tid; i < 128 * 64; i += 256) Ws[i] = W[i];
    const int r = tid >> 6, c = tid & 63;
    const int row0 = blockIdx.x * 4;
    for (int i = tid; i < 4 * 128; i += 256) {
        int rr = i >> 7, kk = i & 127;
        int row = row0 + rr;
        xs[rr][kk] = (row < N) ? x[row * 128 + kk] : 0.f;
    }
    __syncthreads();
    const int row = row0 + r;
    if (row >= N) return;
    float acc = 0.f;
#pragma unroll 8
    for (int k = 0; k < 128; ++k) acc += xs[r][k] * Ws[k * 64 + c];
    ybf[row * 64 + c] = bf16r(acc);
}

// ------- dual gather-mean: nodes [0,NA) from table A / CSR A, [NA,NA+NB) from B -------
// wave per node; 8 lanes per neighbor row (uint4 = 8 bf16), 8-16 neighbors in flight
__global__ __launch_bounds__(256) void k_gather2(
    const u16* __restrict__ yA, const int* __restrict__ nbrA, const int* __restrict__ endA,
    const int* __restrict__ degA, float* __restrict__ aggA, int NA,
    const u16* __restrict__ yB, const int* __restrict__ nbrB, const int* __restrict__ endB,
    const int* __restrict__ degB, float* __restrict__ aggB, int NB) {
    int w = (blockIdx.x * 256 + threadIdx.x) >> 6;
    int lane = threadIdx.x & 63;
    if (w >= NA + NB) return;
    const u16* y; const int* nbr; const int* endp; const int* deg; float* agg; int n;
    if (w < NA) { y = yA; nbr = nbrA; endp = endA; deg = degA; agg = aggA; n = w; }
    else        { y = yB; nbr = nbrB; endp = endB; deg = degB; agg = aggB; n = w - NA; }
    const int q = lane >> 3, t = lane & 7;
    const int d = deg[n];
    const int end = endp[n];
    int j = end - d;
    float a0=0,a1=0,a2=0,a3=0,a4=0,a5=0,a6=0,a7=0;
    float b0=0,b1=0,b2=0,b3=0,b4=0,b5=0,b6=0,b7=0;
    for (; j + 16 <= end; j += 16) {
        int g0 = nbr[j + q], g1 = nbr[j + 8 + q];
        uint4 v0 = *(const uint4*)(y + g0 * 64 + t * 8);
        uint4 v1 = *(const uint4*)(y + g1 * 64 + t * 8);
        a0 += bflo(v0.x); a1 += bfhi(v0.x); a2 += bflo(v0.y); a3 += bfhi(v0.y);
        a4 += bflo(v0.z); a5 += bfhi(v0.z); a6 += bflo(v0.w); a7 += bfhi(v0.w);
        b0 += bflo(v1.x); b1 += bfhi(v1.x); b2 += bflo(v1.y); b3 += bfhi(v1.y);
        b4 += bflo(v1.z); b5 += bfhi(v1.z); b6 += bflo(v1.w); b7 += bfhi(v1.w);
    }
    for (; j + 8 <= end; j += 8) {
        int g0 = nbr[j + q];
        uint4 v0 = *(const uint4*)(y + g0 * 64 + t * 8);
        a0 += bflo(v0.x); a1 += bfhi(v0.x); a2 += bflo(v0.y); a3 += bfhi(v0.y);
        a4 += bflo(v0.z); a5 += bfhi(v0.z); a6 += bflo(v0.w); a7 += bfhi(v0.w);
    }
    if (j + q < end) {
        int g0 = nbr[j + q];
        uint4 v0 = *(const uint4*)(y + g0 * 64 + t * 8);
        a0 += bflo(v0.x); a1 += bfhi(v0.x); a2 += bflo(v0.y); a3 += bfhi(v0.y);
        a4 += bflo(v0.z); a5 += bfhi(v0.z); a6 += bflo(v0.w); a7 += bfhi(v0.w);
    }
    a0 += b0; a1 += b1; a2 += b2; a3 += b3; a4 += b4; a5 += b5; a6 += b6; a7 += b7;
#pragma unroll
    for (int m = 8; m < 64; m <<= 1) {
        a0 += __shfl_xor(a0, m, 64); a1 += __shfl_xor(a1, m, 64);
        a2 += __shfl_xor(a2, m, 64); a3 += __shfl_xor(a3, m, 64);
        a4 += __shfl_xor(a4, m, 64); a5 += __shfl_xor(a5, m, 64);
        a6 += __shfl_xor(a6, m, 64); a7 += __shfl_xor(a7, m, 64);
    }
    if (q == 0) {
        float dinv = 1.0f / (float)max(d, 1);
        float* dst = agg + n * 64 + t * 8;
        float4 o0, o1;
        o0.x = a0 * dinv; o0.y = a1 * dinv; o0.z = a2 * dinv; o0.w = a3 * dinv;
        o1.x = a4 * dinv; o1.y = a5 * dinv; o1.z = a6 * dinv; o1.w = a7 * dinv;
        *(float4*)dst = o0;
        *(float4*)(dst + 4) = o1;
    }
}

// ------- h = act( agg@Wl + b + xdst@Wr ); in-place safe; optional bf16 shadow -------
template <int K2, bool RELU, bool EMIT>
__global__ __launch_bounds__(256) void k_combine2(const float* __restrict__ agg,
                                                  const float* __restrict__ Wl,
                                                  const float* __restrict__ bias,
                                                  const float* __restrict__ xdst,
                                                  const float* __restrict__ Wr,
                                                  float* __restrict__ h,
                                                  u16* __restrict__ hbf, int N) {
    __shared__ float Wls[64 * 64];
    __shared__ float Wrs[K2 * 64];
    __shared__ float as_[4][64];
    __shared__ float xs[4][K2];
    const int tid = threadIdx.x;
    for (int i = tid; i < 64 * 64; i += 256) Wls[i] = Wl[i];
    for (int i = tid; i < K2 * 64; i += 256) Wrs[i] = Wr[i];
    const int r = tid >> 6, c = tid & 63;
    const int row0 = blockIdx.x * 4;
    {
        int row = row0 + r;
        as_[r][c] = (row < N) ? agg[row * 64 + c] : 0.f;
    }
    for (int i = tid; i < 4 * K2; i += 256) {
        int rr = i / K2, kk = i % K2;
        int row = row0 + rr;
        xs[rr][kk] = (row < N) ? xdst[row * K2 + kk] : 0.f;
    }
    __syncthreads();
    const int row = row0 + r;
    if (row >= N) return;
    float acc = bias[c];
#pragma unroll 8
    for (int k = 0; k < 64; ++k) acc += as_[r][k] * Wls[k * 64 + c];
#pragma unroll 8
    for (int k = 0; k < K2; ++k) acc += xs[r][k] * Wrs[k * 64 + c];
    if (RELU) acc = fmaxf(acc, 0.f);
    h[row * 64 + c] = acc;
    if (EMIT) hbf[row * 64 + c] = bf16r(acc);
}

// ------- h = act( agg + b + xdst@Wr ), agg pre-transformed; optional bf16 shadow -------
template <bool RELU, bool EMIT>
__global__ __launch_bounds__(256) void k_combine_id(const float* __restrict__ agg,
                                                    const float* __restrict__ bias,
                                                    const float* __restrict__ xdst,
                                                    const float* __restrict__ Wr,
                                                    float* __restrict__ h,
                                                    u16* __restrict__ hbf, int N) {
    __shared__ float Wrs[64 * 64];
    __shared__ float xs[4][64];
    const int tid = threadIdx.x;
    for (int i = tid; i < 64 * 64; i += 256) Wrs[i] = Wr[i];
    const int r = tid >> 6, c = tid & 63;
    const int row0 = blockIdx.x * 4;
    {
        int row = row0 + r;
        xs[r][c] = (row < N) ? xdst[row * 64 + c] : 0.f;
    }
    __syncthreads();
    const int row = row0 + r;
    if (row >= N) return;
    float acc = bias[c] + agg[row * 64 + c];
#pragma unroll 8
    for (int k = 0; k < 64; ++k) acc += xs[r][k] * Wrs[k * 64 + c];
    if (RELU) acc = fmaxf(acc, 0.f);
    h[row * 64 + c] = acc;
    if (EMIT) hbf[row * 64 + c] = bf16r(acc);
}

// ------- out[e] = dot64(hu[lu[e]], hp[lp[e]]); quarter-wave per edge, float4 -------
__global__ __launch_bounds__(256) void k_classify4(const float* __restrict__ hu,
                                                   const float* __restrict__ hp,
                                                   const int* __restrict__ lu,
                                                   const int* __restrict__ lp,
                                                   float* __restrict__ out, int EL) {
    int w = (blockIdx.x * 256 + threadIdx.x) >> 6;
    int lane = threadIdx.x & 63;
    int q = lane >> 4, t = lane & 15;
    int e = w * 4 + q;
    float v = 0.f;
    if (e < EL) {
        int u = lu[e], p = lp[e];
        float4 a = *(const float4*)(hu + u * 64 + t * 4);
        float4 b = *(const float4*)(hp + p * 64 + t * 4);
        v = a.x * b.x + a.y * b.y + a.z * b.z + a.w * b.w;
    }
#pragma unroll
    for (int m = 1; m < 16; m <<= 1) v += __shfl_xor(v, m, 64);
    if (t == 0 && e < EL) out[e] = v;
}

extern "C" void kernel_launch(void* const* d_in, const int* in_sizes, int n_in,
                              void* d_out, int out_size, void* d_ws, size_t ws_size,
                              hipStream_t stream) {
    const float* x_user    = (const float*)d_in[0];
    const float* x_product = (const float*)d_in[1];
    const float* W1bl = (const float*)d_in[2];
    const float* b1b  = (const float*)d_in[3];
    const float* W1br = (const float*)d_in[4];
    const float* W1rl = (const float*)d_in[5];
    const float* b1r  = (const float*)d_in[6];
    const float* W1rr = (const float*)d_in[7];
    const float* W2bl = (const float*)d_in[8];
    const float* b2b  = (const float*)d_in[9];
    const float* W2br = (const float*)d_in[10];
    const float* W2rl = (const float*)d_in[11];
    const float* b2r  = (const float*)d_in[12];
    const float* W2rr = (const float*)d_in[13];
    const int* esrc = (const int*)d_in[14];
    const int* edst = (const int*)d_in[15];
    const int* lu   = (const int*)d_in[16];
    const int* lp   = (const int*)d_in[17];

    const int NU = in_sizes[0] / 64;
    const int NP = in_sizes[1] / 128;
    const int E  = in_sizes[14];
    const int EL = in_sizes[16];

    // ---- workspace layout (~113 MB) ----
    char* ws = (char*)d_ws;
    size_t off = 0;
    auto alloc = [&](size_t bytes) -> void* {
        void* p = ws + off;
        off += (bytes + 255) & ~(size_t)255;
        return p;
    };
    int*   deg_u = (int*)alloc((size_t)NU * 4);
    int*   deg_p = (int*)alloc((size_t)NP * 4);
    int*   ptr_u = (int*)alloc((size_t)NU * 4);
    int*   ptr_p = (int*)alloc((size_t)NP * 4);
    int*   cnt   = (int*)alloc(256);
    int*   nbr_u = (int*)alloc((size_t)E * 4);
    int*   nbr_p = (int*)alloc((size_t)E * 4);
    float* aggP  = (float*)alloc((size_t)NP * 64 * 4);
    float* aggU  = (float*)alloc((size_t)NU * 64 * 4);
    u16*   bfA   = (u16*)alloc((size_t)NU * 64 * 2);  // x_user_bf, then h_u_bf
    u16*   bfB   = (u16*)alloc((size_t)NP * 64 * 2);  // y_p1_bf,  then h_p_bf
    float* h_p   = (float*)alloc((size_t)NP * 64 * 4);
    float* h_u   = (float*)alloc((size_t)NU * 64 * 4);

    const int E4 = E >> 2, Erem = E & 3;

    // ---- CSR build (both directions) ----
    hipMemsetAsync(deg_u, 0, (size_t)NU * 4, stream);
    hipMemsetAsync(deg_p, 0, (size_t)NP * 4, stream);
    hipMemsetAsync(cnt, 0, 256, stream);
    k_deg4<<<(E4 + 255) / 256, 256, 0, stream>>>((const int4*)esrc, (const int4*)edst, deg_u, deg_p, E4);
    if (Erem) k_deg_tail<<<1, 64, 0, stream>>>(esrc, edst, deg_u, deg_p, E4 * 4, E);
    k_offsets<<<(NU + 255) / 256, 256, 0, stream>>>(deg_u, ptr_u, &cnt[0], NU);
    k_offsets<<<(NP + 255) / 256, 256, 0, stream>>>(deg_p, ptr_p, &cnt[1], NP);
    k_fill4<<<(E4 + 255) / 256, 256, 0, stream>>>((const int4*)esrc, (const int4*)edst, ptr_u, ptr_p, nbr_u, nbr_p, E4);
    if (Erem) k_fill_tail<<<1, 64, 0, stream>>>(esrc, edst, ptr_u, ptr_p, nbr_u, nbr_p, E4 * 4, E);
    // ptr_* now hold END offsets; gathers use end - deg.

    // ---- bf16 shadows for layer-1 aggregation sources ----
    k_cast8<<<(NU * 64 / 8 + 255) / 256, 256, 0, stream>>>(x_user, bfA, NU * 64 / 8);
    k_transform_bf128<<<(NP + 3) / 4, 256, 0, stream>>>(x_product, W1rl, bfB, NP);

    // ---- layer 1: fused dual gather, then combines (emitting bf16 shadows for L2) ----
    k_gather2<<<(NP + NU + 3) / 4, 256, 0, stream>>>(bfA, nbr_p, ptr_p, deg_p, aggP, NP,
                                                     bfB, nbr_u, ptr_u, deg_u, aggU, NU);
    k_combine2<128, true, true><<<(NP + 3) / 4, 256, 0, stream>>>(aggP, W1bl, b1b, x_product, W1br, h_p, bfB, NP);
    k_combine_id<true, true><<<(NU + 3) / 4, 256, 0, stream>>>(aggU, b1r, x_user, W1rr, h_u, bfA, NU);

    // ---- layer 2: fused dual gather, then in-place combines ----
    k_gather2<<<(NP + NU + 3) / 4, 256, 0, stream>>>(bfA, nbr_p, ptr_p, deg_p, aggP, NP,
                                                     bfB, nbr_u, ptr_u, deg_u, aggU, NU);
    k_combine2<64, false, false><<<(NP + 3) / 4, 256, 0, stream>>>(aggP, W2bl, b2b, h_p, W2br, h_p, nullptr, NP);
    k_combine2<64, false, false><<<(NU + 3) / 4, 256, 0, stream>>>(aggU, W2rl, b2r, h_u, W2rr, h_u, nullptr, NU);

    // ---- classifier ----
    k_classify4<<<((EL + 3) / 4 + 3) / 4, 256, 0, stream>>>(h_u, h_p, lu, lp, (float*)d_out, EL);
}

// Round 4
// 784.940 us; speedup vs baseline: 3.1697x; 1.5422x over previous
//
#include <hip/hip_runtime.h>

// 2-layer hetero GraphSAGE, fp32 compute, bf16 gather tables, bucketed CSR build.
// CSR build = counting-sort: coarse bucket (key>>8) partition with LDS-staged
// coalesced flushes, then per-bucket fine fill (degrees + offsets + nbr) with
// all writes confined to the bucket's small L2-hot region. No 16x write amp.

using u16 = unsigned short;
using u32 = unsigned int;

__device__ __forceinline__ u16 bf16r(float f) {            // round-to-nearest-even
    u32 b = __float_as_uint(f);
    b += 0x7fffu + ((b >> 16) & 1u);
    return (u16)(b >> 16);
}
__device__ __forceinline__ float bflo(u32 u) { return __uint_as_float(u << 16); }
__device__ __forceinline__ float bfhi(u32 u) { return __uint_as_float(u & 0xffff0000u); }

#define BSH 8          // bucket = key >> BSH, 256 node ids per bucket
#define MAXB 512       // max buckets per direction (NU=100000 -> 391)
#define CHUNK 4096     // edges per partition block
#define RPT 16         // CHUNK / 256

// ---- pass A: coarse bucket histograms, both directions fused ----
__global__ __launch_bounds__(256) void k_histA(const int* __restrict__ esrc,
                                               const int* __restrict__ edst,
                                               int* __restrict__ bcntP,
                                               int* __restrict__ bcntU,
                                               int NBP, int NBU, int E) {
    __shared__ int hP[MAXB];
    __shared__ int hU[MAXB];
    int tid = threadIdx.x;
    for (int i = tid; i < MAXB; i += 256) { hP[i] = 0; hU[i] = 0; }
    __syncthreads();
    int E4 = E >> 2;
    const int4* s4 = (const int4*)esrc;
    const int4* d4 = (const int4*)edst;
    int stride = gridDim.x * 256;
    for (int i = blockIdx.x * 256 + tid; i < E4; i += stride) {
        int4 s = s4[i], d = d4[i];
        atomicAdd(&hU[s.x >> BSH], 1); atomicAdd(&hU[s.y >> BSH], 1);
        atomicAdd(&hU[s.z >> BSH], 1); atomicAdd(&hU[s.w >> BSH], 1);
        atomicAdd(&hP[d.x >> BSH], 1); atomicAdd(&hP[d.y >> BSH], 1);
        atomicAdd(&hP[d.z >> BSH], 1); atomicAdd(&hP[d.w >> BSH], 1);
    }
    if (blockIdx.x == 0 && tid < (E & 3)) {
        int e = E4 * 4 + tid;
        atomicAdd(&hU[esrc[e] >> BSH], 1);
        atomicAdd(&hP[edst[e] >> BSH], 1);
    }
    __syncthreads();
    for (int i = tid; i < NBP; i += 256) if (hP[i]) atomicAdd(&bcntP[i], hP[i]);
    for (int i = tid; i < NBU; i += 256) if (hU[i]) atomicAdd(&bcntU[i], hU[i]);
}

// ---- scan bucket counts -> bases[NB+1] and working cursor[NB]; block 0 = P, 1 = U ----
__global__ __launch_bounds__(256) void k_scanBuckets(const int* __restrict__ cntP,
                                                     int* __restrict__ basesP,
                                                     int* __restrict__ curP, int NBP,
                                                     const int* __restrict__ cntU,
                                                     int* __restrict__ basesU,
                                                     int* __restrict__ curU, int NBU) {
    const int* cnt; int* bases; int* cur; int NB;
    if (blockIdx.x == 0) { cnt = cntP; bases = basesP; cur = curP; NB = NBP; }
    else                 { cnt = cntU; bases = basesU; cur = curU; NB = NBU; }
    __shared__ int sA[MAXB];
    __shared__ int sB[MAXB];
    int tid = threadIdx.x;
    int v0 = (tid < NB) ? cnt[tid] : 0;
    int v1 = (tid + 256 < NB) ? cnt[tid + 256] : 0;
    sA[tid] = v0; sA[tid + 256] = v1;
    __syncthreads();
    int* src = sA; int* dst = sB;
    for (int off = 1; off < MAXB; off <<= 1) {
        dst[tid] = src[tid] + ((tid >= off) ? src[tid - off] : 0);
        int i2 = tid + 256;
        dst[i2] = src[i2] + ((i2 >= off) ? src[i2 - off] : 0);
        __syncthreads();
        int* t = src; src = dst; dst = t;
    }
    if (tid < NB)       { bases[tid] = src[tid] - v0;             cur[tid] = src[tid] - v0; }
    if (tid + 256 < NB) { bases[tid + 256] = src[tid + 256] - v1; cur[tid + 256] = src[tid + 256] - v1; }
    if (tid == 0) bases[NB] = src[MAXB - 1];
}

// ---- pass B: partition edges into bucket-ordered (key,payload) pairs, coalesced flush ----
__global__ __launch_bounds__(256) void k_partition(const int* __restrict__ keys,
                                                   const int* __restrict__ payload,
                                                   int* __restrict__ cursor,
                                                   uint2* __restrict__ pairs,
                                                   int NB, int E) {
    __shared__ int hist[MAXB];
    __shared__ int sA[MAXB];
    __shared__ int sB[MAXB];
    __shared__ int bx[MAXB];
    __shared__ int gbase[MAXB];
    __shared__ uint2 prs[CHUNK];
    int tid = threadIdx.x;
    int i0 = blockIdx.x * CHUNK;
    int count = min(CHUNK, E - i0);
    for (int i = tid; i < MAXB; i += 256) hist[i] = 0;
    __syncthreads();
    int keyr[RPT], payr[RPT], rankr[RPT];
#pragma unroll
    for (int r = 0; r < RPT; ++r) {
        int idx = r * 256 + tid;
        if (idx < count) {
            int k = keys[i0 + idx];
            keyr[r] = k;
            payr[r] = payload[i0 + idx];
            rankr[r] = atomicAdd(&hist[k >> BSH], 1);
        } else keyr[r] = -1;
    }
    __syncthreads();
    // exclusive scan of hist -> bx (ping-pong, 512 wide)
    sA[tid] = hist[tid]; sA[tid + 256] = hist[tid + 256];
    __syncthreads();
    int* src = sA; int* dst = sB;
    for (int off = 1; off < MAXB; off <<= 1) {
        dst[tid] = src[tid] + ((tid >= off) ? src[tid - off] : 0);
        int i2 = tid + 256;
        dst[i2] = src[i2] + ((i2 >= off) ? src[i2 - off] : 0);
        __syncthreads();
        int* t = src; src = dst; dst = t;
    }
    bx[tid] = src[tid] - hist[tid];
    bx[tid + 256] = src[tid + 256] - hist[tid + 256];
    __syncthreads();
    for (int b = tid; b < NB; b += 256) {
        int c = hist[b];
        gbase[b] = c ? atomicAdd(&cursor[b], c) : 0;
    }
    // stage into LDS in bucket order
#pragma unroll
    for (int r = 0; r < RPT; ++r) {
        if (keyr[r] >= 0)
            prs[bx[keyr[r] >> BSH] + rankr[r]] = make_uint2((u32)keyr[r], (u32)payr[r]);
    }
    __syncthreads();
    // coalesced segment copy-out
    for (int j = tid; j < count; j += 256) {
        uint2 pr = prs[j];
        int b = pr.x >> BSH;
        pairs[gbase[b] + (j - bx[b])] = pr;
    }
}

// ---- pass C: per-bucket fine fill -> nbr, deg, ptr(start); both directions fused ----
__global__ __launch_bounds__(256) void k_bucketFill(
    const uint2* __restrict__ pairsP, const int* __restrict__ basesP, int NBP,
    int* __restrict__ nbr_p, int* __restrict__ deg_p, int* __restrict__ ptr_p, int NP,
    const uint2* __restrict__ pairsU, const int* __restrict__ basesU, int NBU,
    int* __restrict__ nbr_u, int* __restrict__ deg_u, int* __restrict__ ptr_u, int NU) {
    const uint2* pairs; const int* bases; int* nbr; int* deg; int* ptr; int N; int bucket;
    if ((int)blockIdx.x < NBP) {
        pairs = pairsP; bases = basesP; nbr = nbr_p; deg = deg_p; ptr = ptr_p; N = NP;
        bucket = blockIdx.x;
    } else {
        pairs = pairsU; bases = basesU; nbr = nbr_u; deg = deg_u; ptr = ptr_u; N = NU;
        bucket = blockIdx.x - NBP;
    }
    int tid = threadIdx.x;
    int base = bases[bucket];
    int cnt = bases[bucket + 1] - base;
    __shared__ int h[256];
    __shared__ int s[256];
    __shared__ int cur[256];
    h[tid] = 0;
    __syncthreads();
    for (int j = tid; j < cnt; j += 256) atomicAdd(&h[pairs[base + j].x & 255], 1);
    __syncthreads();
    int d = h[tid];
    s[tid] = d;
    __syncthreads();
    for (int off = 1; off < 256; off <<= 1) {
        int v = (tid >= off) ? s[tid - off] : 0;
        __syncthreads();
        s[tid] += v;
        __syncthreads();
    }
    int excl = s[tid] - d;
    int node = bucket * 256 + tid;
    if (node < N) { deg[node] = d; ptr[node] = base + excl; }
    cur[tid] = excl;
    __syncthreads();
    for (int j = tid; j < cnt; j += 256) {
        uint2 pr = pairs[base + j];
        int pos = atomicAdd(&cur[pr.x & 255], 1);
        nbr[base + pos] = pr.y;
    }
}

// ---------------- fp32 table -> bf16 shadow, 8 elems/thread ----------------
__global__ __launch_bounds__(256) void k_cast8(const float* __restrict__ x,
                                               u16* __restrict__ y, int n8) {
    int i = blockIdx.x * 256 + threadIdx.x;
    if (i >= n8) return;
    const float4* x4 = (const float4*)x;
    float4 a = x4[i * 2], b = x4[i * 2 + 1];
    uint4 o;
    o.x = (u32)bf16r(a.x) | ((u32)bf16r(a.y) << 16);
    o.y = (u32)bf16r(a.z) | ((u32)bf16r(a.w) << 16);
    o.z = (u32)bf16r(b.x) | ((u32)bf16r(b.y) << 16);
    o.w = (u32)bf16r(b.z) | ((u32)bf16r(b.w) << 16);
    ((uint4*)y)[i] = o;
}

// ---------------- y_bf[n][c] = bf16( sum_k x[n][k] * W[k][c] ), K=128 ----------------
__global__ __launch_bounds__(256) void k_transform_bf128(const float* __restrict__ x,
                                                         const float* __restrict__ W,
                                                         u16* __restrict__ ybf, int N) {
    __shared__ float Ws[128 * 64];
    __shared__ float xs[4][128];
    const int tid = threadIdx.x;
    for (int i = tid; i < 128 * 64; i += 256) Ws[i] = W[i];
    const int r = tid >> 6, c = tid & 63;
    const int row0 = blockIdx.x * 4;
    for (int i = tid; i < 4 * 128; i += 256) {
        int rr = i >> 7, kk = i & 127;
        int row = row0 + rr;
        xs[rr][kk] = (row < N) ? x[row * 128 + kk] : 0.f;
    }
    __syncthreads();
    const int row = row0 + r;
    if (row >= N) return;
    float acc = 0.f;
#pragma unroll 8
    for (int k = 0; k < 128; ++k) acc += xs[r][k] * Ws[k * 64 + c];
    ybf[row * 64 + c] = bf16r(acc);
}

// ------- dual gather-mean: nodes [0,NA) from table A / CSR A, [NA,NA+NB) from B -------
__global__ __launch_bounds__(256) void k_gather2(
    const u16* __restrict__ yA, const int* __restrict__ nbrA, const int* __restrict__ startA,
    const int* __restrict__ degA, float* __restrict__ aggA, int NA,
    const u16* __restrict__ yB, const int* __restrict__ nbrB, const int* __restrict__ startB,
    const int* __restrict__ degB, float* __restrict__ aggB, int NB) {
    int w = (blockIdx.x * 256 + threadIdx.x) >> 6;
    int lane = threadIdx.x & 63;
    if (w >= NA + NB) return;
    const u16* y; const int* nbr; const int* stp; const int* deg; float* agg; int n;
    if (w < NA) { y = yA; nbr = nbrA; stp = startA; deg = degA; agg = aggA; n = w; }
    else        { y = yB; nbr = nbrB; stp = startB; deg = degB; agg = aggB; n = w - NA; }
    const int q = lane >> 3, t = lane & 7;
    const int d = deg[n];
    int j = stp[n];
    const int end = j + d;
    float a0=0,a1=0,a2=0,a3=0,a4=0,a5=0,a6=0,a7=0;
    float b0=0,b1=0,b2=0,b3=0,b4=0,b5=0,b6=0,b7=0;
    for (; j + 16 <= end; j += 16) {
        int g0 = nbr[j + q], g1 = nbr[j + 8 + q];
        uint4 v0 = *(const uint4*)(y + g0 * 64 + t * 8);
        uint4 v1 = *(const uint4*)(y + g1 * 64 + t * 8);
        a0 += bflo(v0.x); a1 += bfhi(v0.x); a2 += bflo(v0.y); a3 += bfhi(v0.y);
        a4 += bflo(v0.z); a5 += bfhi(v0.z); a6 += bflo(v0.w); a7 += bfhi(v0.w);
        b0 += bflo(v1.x); b1 += bfhi(v1.x); b2 += bflo(v1.y); b3 += bfhi(v1.y);
        b4 += bflo(v1.z); b5 += bfhi(v1.z); b6 += bflo(v1.w); b7 += bfhi(v1.w);
    }
    for (; j + 8 <= end; j += 8) {
        int g0 = nbr[j + q];
        uint4 v0 = *(const uint4*)(y + g0 * 64 + t * 8);
        a0 += bflo(v0.x); a1 += bfhi(v0.x); a2 += bflo(v0.y); a3 += bfhi(v0.y);
        a4 += bflo(v0.z); a5 += bfhi(v0.z); a6 += bflo(v0.w); a7 += bfhi(v0.w);
    }
    if (j + q < end) {
        int g0 = nbr[j + q];
        uint4 v0 = *(const uint4*)(y + g0 * 64 + t * 8);
        a0 += bflo(v0.x); a1 += bfhi(v0.x); a2 += bflo(v0.y); a3 += bfhi(v0.y);
        a4 += bflo(v0.z); a5 += bfhi(v0.z); a6 += bflo(v0.w); a7 += bfhi(v0.w);
    }
    a0 += b0; a1 += b1; a2 += b2; a3 += b3; a4 += b4; a5 += b5; a6 += b6; a7 += b7;
#pragma unroll
    for (int m = 8; m < 64; m <<= 1) {
        a0 += __shfl_xor(a0, m, 64); a1 += __shfl_xor(a1, m, 64);
        a2 += __shfl_xor(a2, m, 64); a3 += __shfl_xor(a3, m, 64);
        a4 += __shfl_xor(a4, m, 64); a5 += __shfl_xor(a5, m, 64);
        a6 += __shfl_xor(a6, m, 64); a7 += __shfl_xor(a7, m, 64);
    }
    if (q == 0) {
        float dinv = 1.0f / (float)max(d, 1);
        float* dstp = agg + n * 64 + t * 8;
        float4 o0, o1;
        o0.x = a0 * dinv; o0.y = a1 * dinv; o0.z = a2 * dinv; o0.w = a3 * dinv;
        o1.x = a4 * dinv; o1.y = a5 * dinv; o1.z = a6 * dinv; o1.w = a7 * dinv;
        *(float4*)dstp = o0;
        *(float4*)(dstp + 4) = o1;
    }
}

// ------- h = act( agg@Wl + b + xdst@Wr ); in-place safe; optional bf16 shadow -------
template <int K2, bool RELU, bool EMIT>
__global__ __launch_bounds__(256) void k_combine2(const float* __restrict__ agg,
                                                  const float* __restrict__ Wl,
                                                  const float* __restrict__ bias,
                                                  const float* __restrict__ xdst,
                                                  const float* __restrict__ Wr,
                                                  float* __restrict__ h,
                                                  u16* __restrict__ hbf, int N) {
    __shared__ float Wls[64 * 64];
    __shared__ float Wrs[K2 * 64];
    __shared__ float as_[4][64];
    __shared__ float xs[4][K2];
    const int tid = threadIdx.x;
    for (int i = tid; i < 64 * 64; i += 256) Wls[i] = Wl[i];
    for (int i = tid; i < K2 * 64; i += 256) Wrs[i] = Wr[i];
    const int r = tid >> 6, c = tid & 63;
    const int row0 = blockIdx.x * 4;
    {
        int row = row0 + r;
        as_[r][c] = (row < N) ? agg[row * 64 + c] : 0.f;
    }
    for (int i = tid; i < 4 * K2; i += 256) {
        int rr = i / K2, kk = i % K2;
        int row = row0 + rr;
        xs[rr][kk] = (row < N) ? xdst[row * K2 + kk] : 0.f;
    }
    __syncthreads();
    const int row = row0 + r;
    if (row >= N) return;
    float acc = bias[c];
#pragma unroll 8
    for (int k = 0; k < 64; ++k) acc += as_[r][k] * Wls[k * 64 + c];
#pragma unroll 8
    for (int k = 0; k < K2; ++k) acc += xs[r][k] * Wrs[k * 64 + c];
    if (RELU) acc = fmaxf(acc, 0.f);
    h[row * 64 + c] = acc;
    if (EMIT) hbf[row * 64 + c] = bf16r(acc);
}

// ------- h = act( agg + b + xdst@Wr ), agg pre-transformed; optional bf16 shadow -------
template <bool RELU, bool EMIT>
__global__ __launch_bounds__(256) void k_combine_id(const float* __restrict__ agg,
                                                    const float* __restrict__ bias,
                                                    const float* __restrict__ xdst,
                                                    const float* __restrict__ Wr,
                                                    float* __restrict__ h,
                                                    u16* __restrict__ hbf, int N) {
    __shared__ float Wrs[64 * 64];
    __shared__ float xs[4][64];
    const int tid = threadIdx.x;
    for (int i = tid; i < 64 * 64; i += 256) Wrs[i] = Wr[i];
    const int r = tid >> 6, c = tid & 63;
    const int row0 = blockIdx.x * 4;
    {
        int row = row0 + r;
        xs[r][c] = (row < N) ? xdst[row * 64 + c] : 0.f;
    }
    __syncthreads();
    const int row = row0 + r;
    if (row >= N) return;
    float acc = bias[c] + agg[row * 64 + c];
#pragma unroll 8
    for (int k = 0; k < 64; ++k) acc += xs[r][k] * Wrs[k * 64 + c];
    if (RELU) acc = fmaxf(acc, 0.f);
    h[row * 64 + c] = acc;
    if (EMIT) hbf[row * 64 + c] = bf16r(acc);
}

// ------- out[e] = dot64(hu[lu[e]], hp[lp[e]]); quarter-wave per edge, float4 -------
__global__ __launch_bounds__(256) void k_classify4(const float* __restrict__ hu,
                                                   const float* __restrict__ hp,
                                                   const int* __restrict__ lu,
                                                   const int* __restrict__ lp,
                                                   float* __restrict__ out, int EL) {
    int w = (blockIdx.x * 256 + threadIdx.x) >> 6;
    int lane = threadIdx.x & 63;
    int q = lane >> 4, t = lane & 15;
    int e = w * 4 + q;
    float v = 0.f;
    if (e < EL) {
        int u = lu[e], p = lp[e];
        float4 a = *(const float4*)(hu + u * 64 + t * 4);
        float4 b = *(const float4*)(hp + p * 64 + t * 4);
        v = a.x * b.x + a.y * b.y + a.z * b.z + a.w * b.w;
    }
#pragma unroll
    for (int m = 1; m < 16; m <<= 1) v += __shfl_xor(v, m, 64);
    if (t == 0 && e < EL) out[e] = v;
}

extern "C" void kernel_launch(void* const* d_in, const int* in_sizes, int n_in,
                              void* d_out, int out_size, void* d_ws, size_t ws_size,
                              hipStream_t stream) {
    const float* x_user    = (const float*)d_in[0];
    const float* x_product = (const float*)d_in[1];
    const float* W1bl = (const float*)d_in[2];
    const float* b1b  = (const float*)d_in[3];
    const float* W1br = (const float*)d_in[4];
    const float* W1rl = (const float*)d_in[5];
    const float* b1r  = (const float*)d_in[6];
    const float* W1rr = (const float*)d_in[7];
    const float* W2bl = (const float*)d_in[8];
    const float* b2b  = (const float*)d_in[9];
    const float* W2br = (const float*)d_in[10];
    const float* W2rl = (const float*)d_in[11];
    const float* b2r  = (const float*)d_in[12];
    const float* W2rr = (const float*)d_in[13];
    const int* esrc = (const int*)d_in[14];
    const int* edst = (const int*)d_in[15];
    const int* lu   = (const int*)d_in[16];
    const int* lp   = (const int*)d_in[17];

    const int NU = in_sizes[0] / 64;
    const int NP = in_sizes[1] / 128;
    const int E  = in_sizes[14];
    const int EL = in_sizes[16];
    const int NBP = (NP + 255) >> BSH;
    const int NBU = (NU + 255) >> BSH;

    // ---- workspace layout ----
    char* ws = (char*)d_ws;
    size_t off = 0;
    auto alloc = [&](size_t bytes) -> void* {
        void* p = ws + off;
        off += (bytes + 255) & ~(size_t)255;
        return p;
    };
    int*   deg_u  = (int*)alloc((size_t)NU * 4);
    int*   deg_p  = (int*)alloc((size_t)NP * 4);
    int*   ptr_u  = (int*)alloc((size_t)NU * 4);
    int*   ptr_p  = (int*)alloc((size_t)NP * 4);
    int*   bcntP  = (int*)alloc((size_t)MAXB * 4);   // contiguous with bcntU: one memset
    int*   bcntU  = (int*)alloc((size_t)MAXB * 4);
    int*   basesP = (int*)alloc((size_t)(MAXB + 1) * 4);
    int*   basesU = (int*)alloc((size_t)(MAXB + 1) * 4);
    int*   curP   = (int*)alloc((size_t)MAXB * 4);
    int*   curU   = (int*)alloc((size_t)MAXB * 4);
    int*   nbr_u  = (int*)alloc((size_t)E * 4);
    int*   nbr_p  = (int*)alloc((size_t)E * 4);
    // union region: pairs (CSR build) then agg (gather onward)
    size_t aggBytes = (size_t)(NP + NU) * 64 * 4;
    size_t pairBytes = (size_t)E * 8 * 2;
    char* uni = (char*)alloc(aggBytes > pairBytes ? aggBytes : pairBytes);
    float* aggP   = (float*)uni;
    float* aggU   = (float*)(uni + (size_t)NP * 64 * 4);
    uint2* pairsP = (uint2*)uni;
    uint2* pairsU = (uint2*)(uni + (size_t)E * 8);
    u16*   bfA    = (u16*)alloc((size_t)NU * 64 * 2);  // x_user_bf, then h_u_bf
    u16*   bfB    = (u16*)alloc((size_t)NP * 64 * 2);  // y_p1_bf,  then h_p_bf
    float* h_p    = (float*)alloc((size_t)NP * 64 * 4);
    float* h_u    = (float*)alloc((size_t)NU * 64 * 4);

    // ---- CSR build: bucketed counting sort, both directions ----
    hipMemsetAsync(bcntP, 0, (size_t)MAXB * 2 * 4, stream);  // bcntP+bcntU contiguous
    k_histA<<<512, 256, 0, stream>>>(esrc, edst, bcntP, bcntU, NBP, NBU, E);
    k_scanBuckets<<<2, 256, 0, stream>>>(bcntP, basesP, curP, NBP, bcntU, basesU, curU, NBU);
    const int pblocks = (E + CHUNK - 1) / CHUNK;
    k_partition<<<pblocks, 256, 0, stream>>>(edst, esrc, curP, pairsP, NBP, E);  // dir P
    k_partition<<<pblocks, 256, 0, stream>>>(esrc, edst, curU, pairsU, NBU, E);  // dir U
    k_bucketFill<<<NBP + NBU, 256, 0, stream>>>(pairsP, basesP, NBP, nbr_p, deg_p, ptr_p, NP,
                                                pairsU, basesU, NBU, nbr_u, deg_u, ptr_u, NU);

    // ---- bf16 shadows for layer-1 aggregation sources ----
    k_cast8<<<(NU * 64 / 8 + 255) / 256, 256, 0, stream>>>(x_user, bfA, NU * 64 / 8);
    k_transform_bf128<<<(NP + 3) / 4, 256, 0, stream>>>(x_product, W1rl, bfB, NP);

    // ---- layer 1: fused dual gather (pairs region now dead -> agg), then combines ----
    k_gather2<<<(NP + NU + 3) / 4, 256, 0, stream>>>(bfA, nbr_p, ptr_p, deg_p, aggP, NP,
                                                     bfB, nbr_u, ptr_u, deg_u, aggU, NU);
    k_combine2<128, true, true><<<(NP + 3) / 4, 256, 0, stream>>>(aggP, W1bl, b1b, x_product, W1br, h_p, bfB, NP);
    k_combine_id<true, true><<<(NU + 3) / 4, 256, 0, stream>>>(aggU, b1r, x_user, W1rr, h_u, bfA, NU);

    // ---- layer 2: fused dual gather, then in-place combines ----
    k_gather2<<<(NP + NU + 3) / 4, 256, 0, stream>>>(bfA, nbr_p, ptr_p, deg_p, aggP, NP,
                                                     bfB, nbr_u, ptr_u, deg_u, aggU, NU);
    k_combine2<64, false, false><<<(NP + 3) / 4, 256, 0, stream>>>(aggP, W2bl, b2b, h_p, W2br, h_p, nullptr, NP);
    k_combine2<64, false, false><<<(NU + 3) / 4, 256, 0, stream>>>(aggU, W2rl, b2r, h_u, W2rr, h_u, nullptr, NU);

    // ---- classifier ----
    k_classify4<<<((EL + 3) / 4 + 3) / 4, 256, 0, stream>>>(h_u, h_p, lu, lp, (float*)d_out, EL);
}

// Round 5
// 574.892 us; speedup vs baseline: 4.3278x; 1.3654x over previous
//
#include <hip/hip_runtime.h>

// 2-layer hetero GraphSAGE, fp32 compute, bf16 gather tables, bucketed CSR build,
// persistent-weight register-tiled combines.

using u16 = unsigned short;
using u32 = unsigned int;

__device__ __forceinline__ u16 bf16r(float f) {            // round-to-nearest-even
    u32 b = __float_as_uint(f);
    b += 0x7fffu + ((b >> 16) & 1u);
    return (u16)(b >> 16);
}
__device__ __forceinline__ float bflo(u32 u) { return __uint_as_float(u << 16); }
__device__ __forceinline__ float bfhi(u32 u) { return __uint_as_float(u & 0xffff0000u); }

#define BSH 8          // bucket = key >> BSH, 256 node ids per bucket
#define MAXB 512       // max buckets per direction (NU=100000 -> 391)
#define CHUNK 4096     // edges per partition block
#define RPT 16         // CHUNK / 256

// ---- pass A: coarse bucket histograms, both directions fused ----
__global__ __launch_bounds__(256) void k_histA(const int* __restrict__ esrc,
                                               const int* __restrict__ edst,
                                               int* __restrict__ bcntP,
                                               int* __restrict__ bcntU,
                                               int NBP, int NBU, int E) {
    __shared__ int hP[MAXB];
    __shared__ int hU[MAXB];
    int tid = threadIdx.x;
    for (int i = tid; i < MAXB; i += 256) { hP[i] = 0; hU[i] = 0; }
    __syncthreads();
    int E4 = E >> 2;
    const int4* s4 = (const int4*)esrc;
    const int4* d4 = (const int4*)edst;
    int stride = gridDim.x * 256;
    for (int i = blockIdx.x * 256 + tid; i < E4; i += stride) {
        int4 s = s4[i], d = d4[i];
        atomicAdd(&hU[s.x >> BSH], 1); atomicAdd(&hU[s.y >> BSH], 1);
        atomicAdd(&hU[s.z >> BSH], 1); atomicAdd(&hU[s.w >> BSH], 1);
        atomicAdd(&hP[d.x >> BSH], 1); atomicAdd(&hP[d.y >> BSH], 1);
        atomicAdd(&hP[d.z >> BSH], 1); atomicAdd(&hP[d.w >> BSH], 1);
    }
    if (blockIdx.x == 0 && tid < (E & 3)) {
        int e = E4 * 4 + tid;
        atomicAdd(&hU[esrc[e] >> BSH], 1);
        atomicAdd(&hP[edst[e] >> BSH], 1);
    }
    __syncthreads();
    for (int i = tid; i < NBP; i += 256) if (hP[i]) atomicAdd(&bcntP[i], hP[i]);
    for (int i = tid; i < NBU; i += 256) if (hU[i]) atomicAdd(&bcntU[i], hU[i]);
}

// ---- scan bucket counts -> bases[NB+1] and working cursor[NB]; block 0 = P, 1 = U ----
__global__ __launch_bounds__(256) void k_scanBuckets(const int* __restrict__ cntP,
                                                     int* __restrict__ basesP,
                                                     int* __restrict__ curP, int NBP,
                                                     const int* __restrict__ cntU,
                                                     int* __restrict__ basesU,
                                                     int* __restrict__ curU, int NBU) {
    const int* cnt; int* bases; int* cur; int NB;
    if (blockIdx.x == 0) { cnt = cntP; bases = basesP; cur = curP; NB = NBP; }
    else                 { cnt = cntU; bases = basesU; cur = curU; NB = NBU; }
    __shared__ int sA[MAXB];
    __shared__ int sB[MAXB];
    int tid = threadIdx.x;
    int v0 = (tid < NB) ? cnt[tid] : 0;
    int v1 = (tid + 256 < NB) ? cnt[tid + 256] : 0;
    sA[tid] = v0; sA[tid + 256] = v1;
    __syncthreads();
    int* src = sA; int* dst = sB;
    for (int off = 1; off < MAXB; off <<= 1) {
        dst[tid] = src[tid] + ((tid >= off) ? src[tid - off] : 0);
        int i2 = tid + 256;
        dst[i2] = src[i2] + ((i2 >= off) ? src[i2 - off] : 0);
        __syncthreads();
        int* t = src; src = dst; dst = t;
    }
    if (tid < NB)       { bases[tid] = src[tid] - v0;             cur[tid] = src[tid] - v0; }
    if (tid + 256 < NB) { bases[tid + 256] = src[tid + 256] - v1; cur[tid + 256] = src[tid + 256] - v1; }
    if (tid == 0) bases[NB] = src[MAXB - 1];
}

// ---- pass B: partition edges into bucket-ordered (key,payload) pairs, coalesced flush ----
__global__ __launch_bounds__(256) void k_partition(const int* __restrict__ keys,
                                                   const int* __restrict__ payload,
                                                   int* __restrict__ cursor,
                                                   uint2* __restrict__ pairs,
                                                   int NB, int E) {
    __shared__ int hist[MAXB];
    __shared__ int sA[MAXB];
    __shared__ int sB[MAXB];
    __shared__ int bx[MAXB];
    __shared__ int gbase[MAXB];
    __shared__ uint2 prs[CHUNK];
    int tid = threadIdx.x;
    int i0 = blockIdx.x * CHUNK;
    int count = min(CHUNK, E - i0);
    for (int i = tid; i < MAXB; i += 256) hist[i] = 0;
    __syncthreads();
    int keyr[RPT], payr[RPT], rankr[RPT];
#pragma unroll
    for (int r = 0; r < RPT; ++r) {
        int idx = r * 256 + tid;
        if (idx < count) {
            int k = keys[i0 + idx];
            keyr[r] = k;
            payr[r] = payload[i0 + idx];
            rankr[r] = atomicAdd(&hist[k >> BSH], 1);
        } else keyr[r] = -1;
    }
    __syncthreads();
    // exclusive scan of hist -> bx (ping-pong, 512 wide)
    sA[tid] = hist[tid]; sA[tid + 256] = hist[tid + 256];
    __syncthreads();
    int* src = sA; int* dst = sB;
    for (int off = 1; off < MAXB; off <<= 1) {
        dst[tid] = src[tid] + ((tid >= off) ? src[tid - off] : 0);
        int i2 = tid + 256;
        dst[i2] = src[i2] + ((i2 >= off) ? src[i2 - off] : 0);
        __syncthreads();
        int* t = src; src = dst; dst = t;
    }
    bx[tid] = src[tid] - hist[tid];
    bx[tid + 256] = src[tid + 256] - hist[tid + 256];
    __syncthreads();
    for (int b = tid; b < NB; b += 256) {
        int c = hist[b];
        gbase[b] = c ? atomicAdd(&cursor[b], c) : 0;
    }
    // stage into LDS in bucket order
#pragma unroll
    for (int r = 0; r < RPT; ++r) {
        if (keyr[r] >= 0)
            prs[bx[keyr[r] >> BSH] + rankr[r]] = make_uint2((u32)keyr[r], (u32)payr[r]);
    }
    __syncthreads();
    // coalesced segment copy-out
    for (int j = tid; j < count; j += 256) {
        uint2 pr = prs[j];
        int b = pr.x >> BSH;
        pairs[gbase[b] + (j - bx[b])] = pr;
    }
}

// ---- pass C: per-bucket fine fill -> nbr, deg, ptr(start); both directions fused ----
__global__ __launch_bounds__(256) void k_bucketFill(
    const uint2* __restrict__ pairsP, const int* __restrict__ basesP, int NBP,
    int* __restrict__ nbr_p, int* __restrict__ deg_p, int* __restrict__ ptr_p, int NP,
    const uint2* __restrict__ pairsU, const int* __restrict__ basesU, int NBU,
    int* __restrict__ nbr_u, int* __restrict__ deg_u, int* __restrict__ ptr_u, int NU) {
    const uint2* pairs; const int* bases; int* nbr; int* deg; int* ptr; int N; int bucket;
    if ((int)blockIdx.x < NBP) {
        pairs = pairsP; bases = basesP; nbr = nbr_p; deg = deg_p; ptr = ptr_p; N = NP;
        bucket = blockIdx.x;
    } else {
        pairs = pairsU; bases = basesU; nbr = nbr_u; deg = deg_u; ptr = ptr_u; N = NU;
        bucket = blockIdx.x - NBP;
    }
    int tid = threadIdx.x;
    int base = bases[bucket];
    int cnt = bases[bucket + 1] - base;
    __shared__ int h[256];
    __shared__ int s[256];
    __shared__ int cur[256];
    h[tid] = 0;
    __syncthreads();
    for (int j = tid; j < cnt; j += 256) atomicAdd(&h[pairs[base + j].x & 255], 1);
    __syncthreads();
    int d = h[tid];
    s[tid] = d;
    __syncthreads();
    for (int off = 1; off < 256; off <<= 1) {
        int v = (tid >= off) ? s[tid - off] : 0;
        __syncthreads();
        s[tid] += v;
        __syncthreads();
    }
    int excl = s[tid] - d;
    int node = bucket * 256 + tid;
    if (node < N) { deg[node] = d; ptr[node] = base + excl; }
    cur[tid] = excl;
    __syncthreads();
    for (int j = tid; j < cnt; j += 256) {
        uint2 pr = pairs[base + j];
        int pos = atomicAdd(&cur[pr.x & 255], 1);
        nbr[base + pos] = pr.y;
    }
}

// ---------------- fp32 table -> bf16 shadow, 8 elems/thread ----------------
__global__ __launch_bounds__(256) void k_cast8(const float* __restrict__ x,
                                               u16* __restrict__ y, int n8) {
    int i = blockIdx.x * 256 + threadIdx.x;
    if (i >= n8) return;
    const float4* x4 = (const float4*)x;
    float4 a = x4[i * 2], b = x4[i * 2 + 1];
    uint4 o;
    o.x = (u32)bf16r(a.x) | ((u32)bf16r(a.y) << 16);
    o.y = (u32)bf16r(a.z) | ((u32)bf16r(a.w) << 16);
    o.z = (u32)bf16r(b.x) | ((u32)bf16r(b.y) << 16);
    o.w = (u32)bf16r(b.z) | ((u32)bf16r(b.w) << 16);
    ((uint4*)y)[i] = o;
}

// ---------------- y_bf[n][c] = bf16( sum_k x[n][k] * W[k][c] ), K=128 ----------------
__global__ __launch_bounds__(256) void k_transform_bf128(const float* __restrict__ x,
                                                         const float* __restrict__ W,
                                                         u16* __restrict__ ybf, int N) {
    __shared__ float Ws[128 * 64];
    __shared__ float xs[4][128];
    const int tid = threadIdx.x;
    for (int i = tid; i < 128 * 64; i += 256) Ws[i] = W[i];
    const int r = tid >> 6, c = tid & 63;
    const int row0 = blockIdx.x * 4;
    for (int i = tid; i < 4 * 128; i += 256) {
        int rr = i >> 7, kk = i & 127;
        int row = row0 + rr;
        xs[rr][kk] = (row < N) ? x[row * 128 + kk] : 0.f;
    }
    __syncthreads();
    const int row = row0 + r;
    if (row >= N) return;
    float acc = 0.f;
#pragma unroll 8
    for (int k = 0; k < 128; ++k) acc += xs[r][k] * Ws[k * 64 + c];
    ybf[row * 64 + c] = bf16r(acc);
}

// ------- dual gather-mean: nodes [0,NA) from table A / CSR A, [NA,NA+NB) from B -------
__global__ __launch_bounds__(256) void k_gather2(
    const u16* __restrict__ yA, const int* __restrict__ nbrA, const int* __restrict__ startA,
    const int* __restrict__ degA, float* __restrict__ aggA, int NA,
    const u16* __restrict__ yB, const int* __restrict__ nbrB, const int* __restrict__ startB,
    const int* __restrict__ degB, float* __restrict__ aggB, int NB) {
    int w = (blockIdx.x * 256 + threadIdx.x) >> 6;
    int lane = threadIdx.x & 63;
    if (w >= NA + NB) return;
    const u16* y; const int* nbr; const int* stp; const int* deg; float* agg; int n;
    if (w < NA) { y = yA; nbr = nbrA; stp = startA; deg = degA; agg = aggA; n = w; }
    else        { y = yB; nbr = nbrB; stp = startB; deg = degB; agg = aggB; n = w - NA; }
    const int q = lane >> 3, t = lane & 7;
    const int d = deg[n];
    int j = stp[n];
    const int end = j + d;
    float a0=0,a1=0,a2=0,a3=0,a4=0,a5=0,a6=0,a7=0;
    float b0=0,b1=0,b2=0,b3=0,b4=0,b5=0,b6=0,b7=0;
    for (; j + 16 <= end; j += 16) {
        int g0 = nbr[j + q], g1 = nbr[j + 8 + q];
        uint4 v0 = *(const uint4*)(y + g0 * 64 + t * 8);
        uint4 v1 = *(const uint4*)(y + g1 * 64 + t * 8);
        a0 += bflo(v0.x); a1 += bfhi(v0.x); a2 += bflo(v0.y); a3 += bfhi(v0.y);
        a4 += bflo(v0.z); a5 += bfhi(v0.z); a6 += bflo(v0.w); a7 += bfhi(v0.w);
        b0 += bflo(v1.x); b1 += bfhi(v1.x); b2 += bflo(v1.y); b3 += bfhi(v1.y);
        b4 += bflo(v1.z); b5 += bfhi(v1.z); b6 += bflo(v1.w); b7 += bfhi(v1.w);
    }
    for (; j + 8 <= end; j += 8) {
        int g0 = nbr[j + q];
        uint4 v0 = *(const uint4*)(y + g0 * 64 + t * 8);
        a0 += bflo(v0.x); a1 += bfhi(v0.x); a2 += bflo(v0.y); a3 += bfhi(v0.y);
        a4 += bflo(v0.z); a5 += bfhi(v0.z); a6 += bflo(v0.w); a7 += bfhi(v0.w);
    }
    if (j + q < end) {
        int g0 = nbr[j + q];
        uint4 v0 = *(const uint4*)(y + g0 * 64 + t * 8);
        a0 += bflo(v0.x); a1 += bfhi(v0.x); a2 += bflo(v0.y); a3 += bfhi(v0.y);
        a4 += bflo(v0.z); a5 += bfhi(v0.z); a6 += bflo(v0.w); a7 += bfhi(v0.w);
    }
    a0 += b0; a1 += b1; a2 += b2; a3 += b3; a4 += b4; a5 += b5; a6 += b6; a7 += b7;
#pragma unroll
    for (int m = 8; m < 64; m <<= 1) {
        a0 += __shfl_xor(a0, m, 64); a1 += __shfl_xor(a1, m, 64);
        a2 += __shfl_xor(a2, m, 64); a3 += __shfl_xor(a3, m, 64);
        a4 += __shfl_xor(a4, m, 64); a5 += __shfl_xor(a5, m, 64);
        a6 += __shfl_xor(a6, m, 64); a7 += __shfl_xor(a7, m, 64);
    }
    if (q == 0) {
        float dinv = 1.0f / (float)max(d, 1);
        float* dstp = agg + n * 64 + t * 8;
        float4 o0, o1;
        o0.x = a0 * dinv; o0.y = a1 * dinv; o0.z = a2 * dinv; o0.w = a3 * dinv;
        o1.x = a4 * dinv; o1.y = a5 * dinv; o1.z = a6 * dinv; o1.w = a7 * dinv;
        *(float4*)dstp = o0;
        *(float4*)(dstp + 4) = o1;
    }
}

// ======= persistent-weight register-tiled combine =======
// h[row][c] = act( (PRE ? pre[row][c] : 0) + (BIAS ? bias[c] : 0) + x[row][:] @ W )
// Small grid; weights staged to LDS ONCE per block; grid-stride over ROWS-row tiles.
// Thread computes RR=ROWS/16 rows x 4 cols in registers; 2 ds_read_b128 per 16 FMA.
#define FMA_ROW(ACC, O, W4) \
    ACC[0] += (O) * (W4).x; ACC[1] += (O) * (W4).y; \
    ACC[2] += (O) * (W4).z; ACC[3] += (O) * (W4).w;

template <int K, int ROWS, bool RELU, bool EMIT, bool PRE, bool BIAS>
__global__ __launch_bounds__(256) void k_ctile(const float* __restrict__ pre,
                                               const float* __restrict__ bias,
                                               const float* __restrict__ x,
                                               const float* __restrict__ W,
                                               float* __restrict__ h,
                                               u16* __restrict__ hbf, int N) {
    constexpr int RR = ROWS / 16;       // rows per thread
    constexpr int STRIDE = K + 4;       // op row pad: keeps b128 aligned, banks spread
    constexpr int KF4 = K / 4;
    __shared__ float Ws[K * 64];
    __shared__ float op[ROWS * STRIDE];
    const int tid = threadIdx.x;
    for (int i = tid; i < K * 16; i += 256)
        ((float4*)Ws)[i] = ((const float4*)W)[i];
    const int c4 = (tid & 15) * 4;
    const int rb = (tid >> 4) * RR;
    float bx_ = 0.f, by_ = 0.f, bz_ = 0.f, bw_ = 0.f;
    if (BIAS) {
        float4 b4 = *(const float4*)(bias + c4);
        bx_ = b4.x; by_ = b4.y; bz_ = b4.z; bw_ = b4.w;
    }
    const int ntiles = (N + ROWS - 1) / ROWS;
    for (int tile = blockIdx.x; tile < ntiles; tile += gridDim.x) {
        const int row0 = tile * ROWS;
        __syncthreads();  // protect op reuse (also orders first-iter Ws staging)
        for (int i = tid; i < ROWS * KF4; i += 256) {
            int r = i / KF4, k4 = (i % KF4) * 4;
            int row = row0 + r;
            float4 v = make_float4(0.f, 0.f, 0.f, 0.f);
            if (row < N) v = *(const float4*)(x + (size_t)row * K + k4);
            *(float4*)(op + r * STRIDE + k4) = v;
        }
        __syncthreads();
        float acc[RR][4];
#pragma unroll
        for (int i = 0; i < RR; ++i) {
            float px = 0.f, py = 0.f, pz = 0.f, pw = 0.f;
            if (PRE) {
                int row = row0 + rb + i;
                if (row < N) {
                    float4 p = *(const float4*)(pre + row * 64 + c4);
                    px = p.x; py = p.y; pz = p.z; pw = p.w;
                }
            }
            acc[i][0] = bx_ + px; acc[i][1] = by_ + py;
            acc[i][2] = bz_ + pz; acc[i][3] = bw_ + pw;
        }
        for (int kk = 0; kk < K; kk += 4) {
            float4 w0 = *(const float4*)(Ws + (kk + 0) * 64 + c4);
            float4 w1 = *(const float4*)(Ws + (kk + 1) * 64 + c4);
            float4 w2 = *(const float4*)(Ws + (kk + 2) * 64 + c4);
            float4 w3 = *(const float4*)(Ws + (kk + 3) * 64 + c4);
#pragma unroll
            for (int i = 0; i < RR; ++i) {
                float4 o = *(const float4*)(op + (rb + i) * STRIDE + kk);
                FMA_ROW(acc[i], o.x, w0);
                FMA_ROW(acc[i], o.y, w1);
                FMA_ROW(acc[i], o.z, w2);
                FMA_ROW(acc[i], o.w, w3);
            }
        }
#pragma unroll
        for (int i = 0; i < RR; ++i) {
            int row = row0 + rb + i;
            if (row >= N) continue;
            float v0 = acc[i][0], v1 = acc[i][1], v2 = acc[i][2], v3 = acc[i][3];
            if (RELU) {
                v0 = fmaxf(v0, 0.f); v1 = fmaxf(v1, 0.f);
                v2 = fmaxf(v2, 0.f); v3 = fmaxf(v3, 0.f);
            }
            *(float4*)(h + row * 64 + c4) = make_float4(v0, v1, v2, v3);
            if (EMIT) {
                uint2 o;
                o.x = (u32)bf16r(v0) | ((u32)bf16r(v1) << 16);
                o.y = (u32)bf16r(v2) | ((u32)bf16r(v3) << 16);
                *(uint2*)(hbf + row * 64 + c4) = o;
            }
        }
    }
}

// ------- out[e] = dot64(hu[lu[e]], hp[lp[e]]); quarter-wave per edge, float4 -------
__global__ __launch_bounds__(256) void k_classify4(const float* __restrict__ hu,
                                                   const float* __restrict__ hp,
                                                   const int* __restrict__ lu,
                                                   const int* __restrict__ lp,
                                                   float* __restrict__ out, int EL) {
    int w = (blockIdx.x * 256 + threadIdx.x) >> 6;
    int lane = threadIdx.x & 63;
    int q = lane >> 4, t = lane & 15;
    int e = w * 4 + q;
    float v = 0.f;
    if (e < EL) {
        int u = lu[e], p = lp[e];
        float4 a = *(const float4*)(hu + u * 64 + t * 4);
        float4 b = *(const float4*)(hp + p * 64 + t * 4);
        v = a.x * b.x + a.y * b.y + a.z * b.z + a.w * b.w;
    }
#pragma unroll
    for (int m = 1; m < 16; m <<= 1) v += __shfl_xor(v, m, 64);
    if (t == 0 && e < EL) out[e] = v;
}

extern "C" void kernel_launch(void* const* d_in, const int* in_sizes, int n_in,
                              void* d_out, int out_size, void* d_ws, size_t ws_size,
                              hipStream_t stream) {
    const float* x_user    = (const float*)d_in[0];
    const float* x_product = (const float*)d_in[1];
    const float* W1bl = (const float*)d_in[2];
    const float* b1b  = (const float*)d_in[3];
    const float* W1br = (const float*)d_in[4];
    const float* W1rl = (const float*)d_in[5];
    const float* b1r  = (const float*)d_in[6];
    const float* W1rr = (const float*)d_in[7];
    const float* W2bl = (const float*)d_in[8];
    const float* b2b  = (const float*)d_in[9];
    const float* W2br = (const float*)d_in[10];
    const float* W2rl = (const float*)d_in[11];
    const float* b2r  = (const float*)d_in[12];
    const float* W2rr = (const float*)d_in[13];
    const int* esrc = (const int*)d_in[14];
    const int* edst = (const int*)d_in[15];
    const int* lu   = (const int*)d_in[16];
    const int* lp   = (const int*)d_in[17];

    const int NU = in_sizes[0] / 64;
    const int NP = in_sizes[1] / 128;
    const int E  = in_sizes[14];
    const int EL = in_sizes[16];
    const int NBP = (NP + 255) >> BSH;
    const int NBU = (NU + 255) >> BSH;

    // ---- workspace layout ----
    char* ws = (char*)d_ws;
    size_t off = 0;
    auto alloc = [&](size_t bytes) -> void* {
        void* p = ws + off;
        off += (bytes + 255) & ~(size_t)255;
        return p;
    };
    int*   deg_u  = (int*)alloc((size_t)NU * 4);
    int*   deg_p  = (int*)alloc((size_t)NP * 4);
    int*   ptr_u  = (int*)alloc((size_t)NU * 4);
    int*   ptr_p  = (int*)alloc((size_t)NP * 4);
    int*   bcntP  = (int*)alloc((size_t)MAXB * 4);   // contiguous with bcntU: one memset
    int*   bcntU  = (int*)alloc((size_t)MAXB * 4);
    int*   basesP = (int*)alloc((size_t)(MAXB + 1) * 4);
    int*   basesU = (int*)alloc((size_t)(MAXB + 1) * 4);
    int*   curP   = (int*)alloc((size_t)MAXB * 4);
    int*   curU   = (int*)alloc((size_t)MAXB * 4);
    int*   nbr_u  = (int*)alloc((size_t)E * 4);
    int*   nbr_p  = (int*)alloc((size_t)E * 4);
    // union region: pairs (CSR build) then agg (gather onward)
    size_t aggBytes = (size_t)(NP + NU) * 64 * 4;
    size_t pairBytes = (size_t)E * 8 * 2;
    char* uni = (char*)alloc(aggBytes > pairBytes ? aggBytes : pairBytes);
    float* aggP   = (float*)uni;
    float* aggU   = (float*)(uni + (size_t)NP * 64 * 4);
    uint2* pairsP = (uint2*)uni;
    uint2* pairsU = (uint2*)(uni + (size_t)E * 8);
    u16*   bfA    = (u16*)alloc((size_t)NU * 64 * 2);  // x_user_bf, then h_u_bf
    u16*   bfB    = (u16*)alloc((size_t)NP * 64 * 2);  // y_p1_bf,  then h_p_bf
    float* h_p    = (float*)alloc((size_t)NP * 64 * 4);
    float* h_u    = (float*)alloc((size_t)NU * 64 * 4);

    // ---- CSR build: bucketed counting sort, both directions ----
    hipMemsetAsync(bcntP, 0, (size_t)MAXB * 2 * 4, stream);  // bcntP+bcntU contiguous
    k_histA<<<512, 256, 0, stream>>>(esrc, edst, bcntP, bcntU, NBP, NBU, E);
    k_scanBuckets<<<2, 256, 0, stream>>>(bcntP, basesP, curP, NBP, bcntU, basesU, curU, NBU);
    const int pblocks = (E + CHUNK - 1) / CHUNK;
    k_partition<<<pblocks, 256, 0, stream>>>(edst, esrc, curP, pairsP, NBP, E);  // dir P
    k_partition<<<pblocks, 256, 0, stream>>>(esrc, edst, curU, pairsU, NBU, E);  // dir U
    k_bucketFill<<<NBP + NBU, 256, 0, stream>>>(pairsP, basesP, NBP, nbr_p, deg_p, ptr_p, NP,
                                                pairsU, basesU, NBU, nbr_u, deg_u, ptr_u, NU);

    // ---- bf16 shadows for layer-1 aggregation sources ----
    k_cast8<<<(NU * 64 / 8 + 255) / 256, 256, 0, stream>>>(x_user, bfA, NU * 64 / 8);
    k_transform_bf128<<<(NP + 3) / 4, 256, 0, stream>>>(x_product, W1rl, bfB, NP);

    const int tP64 = (NP + 63) / 64, tU64 = (NU + 63) / 64, tP32 = (NP + 31) / 32;
    auto cap = [](int t, int c) { return t < c ? t : c; };

    // ---- layer 1: fused dual gather (pairs region now dead -> agg), then combines ----
    k_gather2<<<(NP + NU + 3) / 4, 256, 0, stream>>>(bfA, nbr_p, ptr_p, deg_p, aggP, NP,
                                                     bfB, nbr_u, ptr_u, deg_u, aggU, NU);
    // h_p = relu(aggP@W1bl + b1b + x_product@W1br), split in 2 passes (LDS<=64KB)
    k_ctile<64, 64, false, false, false, true><<<cap(tP64, 1024), 256, 0, stream>>>(
        nullptr, b1b, aggP, W1bl, h_p, nullptr, NP);
    k_ctile<128, 32, true, true, true, false><<<cap(tP32, 768), 256, 0, stream>>>(
        h_p, nullptr, x_product, W1br, h_p, bfB, NP);
    // h_u = relu(aggU + b1r + x_user@W1rr)  (aggU pre-transformed by k_transform_bf128 path)
    k_ctile<64, 64, true, true, true, true><<<cap(tU64, 1024), 256, 0, stream>>>(
        aggU, b1r, x_user, W1rr, h_u, bfA, NU);

    // ---- layer 2: fused dual gather, then split combines (p1 in-place on agg) ----
    k_gather2<<<(NP + NU + 3) / 4, 256, 0, stream>>>(bfA, nbr_p, ptr_p, deg_p, aggP, NP,
                                                     bfB, nbr_u, ptr_u, deg_u, aggU, NU);
    k_ctile<64, 64, false, false, false, true><<<cap(tP64, 1024), 256, 0, stream>>>(
        nullptr, b2b, aggP, W2bl, aggP, nullptr, NP);          // aggP = aggP@W2bl + b2b
    k_ctile<64, 64, false, false, false, true><<<cap(tU64, 1024), 256, 0, stream>>>(
        nullptr, b2r, aggU, W2rl, aggU, nullptr, NU);          // aggU = aggU@W2rl + b2r
    k_ctile<64, 64, false, false, true, false><<<cap(tP64, 1024), 256, 0, stream>>>(
        aggP, nullptr, h_p, W2br, h_p, nullptr, NP);           // h_p = aggP + h_p@W2br
    k_ctile<64, 64, false, false, true, false><<<cap(tU64, 1024), 256, 0, stream>>>(
        aggU, nullptr, h_u, W2rr, h_u, nullptr, NU);           // h_u = aggU + h_u@W2rr

    // ---- classifier ----
    k_classify4<<<((EL + 3) / 4 + 3) / 4, 256, 0, stream>>>(h_u, h_p, lu, lp, (float*)d_out, EL);
}